// Round 3
// baseline (567.327 us; speedup 1.0000x reference)
//
#include <hip/hip_runtime.h>

typedef float f32x4 __attribute__((ext_vector_type(4)));
typedef short s16x8 __attribute__((ext_vector_type(8)));

#define N_OUT 66049
#define M_DIM 1024
#define K_DIM 1024
#define NPANEL 259           // ceil(66049/256)
#define NT 16                // K_DIM / 64

// round-to-nearest-even f32 -> bf16 (finite inputs)
__device__ __forceinline__ ushort f2bf(float f) {
    union { float f; unsigned u; } x; x.f = f;
    unsigned r = x.u + 0x7fffu + ((x.u >> 16) & 1u);
    return (ushort)(r >> 16);
}

// 16B global -> LDS direct (wave-uniform LDS base + lane*16; global addr per-lane)
__device__ __forceinline__ void lds_load16(const void* g, void* l) {
    auto gp = reinterpret_cast<const __attribute__((address_space(1))) char*>(
        reinterpret_cast<uintptr_t>(g));
    auto lp = reinterpret_cast<__attribute__((address_space(3))) char*>(
        reinterpret_cast<uintptr_t>(l));
    __builtin_amdgcn_global_load_lds(gp, lp, 16, 0, 0);
}

// ---------------- x = concat(noise, embed[orders]) : [1024][116] ----------------
__global__ void build_x(const float* __restrict__ noise, const int* __restrict__ orders,
                        const float* __restrict__ emb, float* __restrict__ x)
{
    int idx = blockIdx.x * 256 + threadIdx.x;
    if (idx >= 1024 * 116) return;
    int b = idx / 116, c = idx - b * 116;
    float v = (c < 100) ? noise[b * 100 + c] : emb[orders[b] * 16 + (c - 100)];
    x[idx] = v;
}

// ---------------- small fp32 GEMM: C = relu(A@W + b), 64x64 tile ----------------
template <bool OUT_BF16>
__global__ __launch_bounds__(256) void gemm_relu(
    const float* __restrict__ A, const float* __restrict__ W,
    const float* __restrict__ bias, void* __restrict__ Cout,
    int M, int N, int K)
{
    __shared__ __align__(16) float As[16][68];  // [k][m], padded
    __shared__ __align__(16) float Ws[16][68];  // [k][n], padded
    const int tid = threadIdx.x;
    const int m0 = blockIdx.x * 64, n0 = blockIdx.y * 64;
    const int tr = tid >> 4, tc = tid & 15;
    float acc[4][4] = {};
    for (int k0 = 0; k0 < K; k0 += 16) {
        #pragma unroll
        for (int e = 0; e < 4; ++e) {
            int idx = e * 256 + tid;
            int r = idx >> 4, c = idx & 15;
            As[c][r] = (k0 + c < K) ? A[(size_t)(m0 + r) * K + k0 + c] : 0.f;
            int rw = idx >> 6, cw = idx & 63;
            Ws[rw][cw] = (k0 + rw < K) ? W[(size_t)(k0 + rw) * N + n0 + cw] : 0.f;
        }
        __syncthreads();
        #pragma unroll
        for (int kk = 0; kk < 16; ++kk) {
            f32x4 a = *reinterpret_cast<const f32x4*>(&As[kk][tr * 4]);
            f32x4 b = *reinterpret_cast<const f32x4*>(&Ws[kk][tc * 4]);
            #pragma unroll
            for (int i = 0; i < 4; ++i)
                #pragma unroll
                for (int j = 0; j < 4; ++j)
                    acc[i][j] = fmaf(a[i], b[j], acc[i][j]);
        }
        __syncthreads();
    }
    f32x4 bo = *reinterpret_cast<const f32x4*>(&bias[n0 + tc * 4]);
    #pragma unroll
    for (int i = 0; i < 4; ++i) {
        int m = m0 + tr * 4 + i;
        if (OUT_BF16) {
            ushort4 u;
            u.x = f2bf(fmaxf(acc[i][0] + bo[0], 0.f));
            u.y = f2bf(fmaxf(acc[i][1] + bo[1], 0.f));
            u.z = f2bf(fmaxf(acc[i][2] + bo[2], 0.f));
            u.w = f2bf(fmaxf(acc[i][3] + bo[3], 0.f));
            *reinterpret_cast<ushort4*>(&((ushort*)Cout)[(size_t)m * N + n0 + tc * 4]) = u;
        } else {
            f32x4 v;
            #pragma unroll
            for (int j = 0; j < 4; ++j) v[j] = fmaxf(acc[i][j] + bo[j], 0.f);
            *reinterpret_cast<f32x4*>(&((float*)Cout)[(size_t)m * N + n0 + tc * 4]) = v;
        }
    }
}

// ------------- convert W_out (f32 [K][N]) -> Bp (bf16, [panel256][kt][kbl(8)][nl(256)][kj8]) -------------
// Unit U holds k = kt*64 + kbl*8 + kj, col = panel*256 + nl. Each (panel,kt) block is a
// contiguous 32 KB chunk laid out exactly like the gemm's Blds -> linear global_load_lds.
__global__ __launch_bounds__(256) void convert_wout(
    const float* __restrict__ Wout, ushort* __restrict__ Bp)
{
    const size_t U = (size_t)blockIdx.x * 256 + threadIdx.x;   // < 259*32768
    const int nl  = (int)(U & 255);
    const int kbl = (int)((U >> 8) & 7);
    const int kt  = (int)((U >> 11) & 15);
    const int p   = (int)(U >> 15);
    int col = p * 256 + nl;
    if (col > N_OUT - 1) col = N_OUT - 1;   // last panel: clamp (cols never stored)
    const float* src = Wout + (size_t)(kt * 64 + kbl * 8) * N_OUT + col;
    s16x8 v;
    #pragma unroll
    for (int i = 0; i < 8; ++i) v[i] = (short)f2bf(src[(size_t)i * N_OUT]);
    *reinterpret_cast<s16x8*>(Bp + U * 8) = v;
}

// ---------------- big GEMM: out = sigmoid(h3(bf16) @ Bp(bf16) + bout) ----------------
// 256x256 tile, BK=64, 8 waves (2M x 4N), 8-phase counted-vmcnt schedule (T2+T3+T4+T5).
__global__ __launch_bounds__(512, 2) void gemm_out(
    const ushort* __restrict__ h3, const ushort* __restrict__ Bp,
    const float* __restrict__ bout, float* __restrict__ out)
{
    // A: [r(256)][cc(8 units of 8 bf16)], source pre-swizzled so LDS[r][cc]=global[r][cc^(r&7)]
    __shared__ __align__(16) ushort Alds[2][16384];   // 2 x 32 KB
    // B: [kbl(8)][nl(256)][kj(8)] — matches Bp global layout (linear copy)
    __shared__ __align__(16) ushort Blds[2][16384];   // 2 x 32 KB

    const int tid  = threadIdx.x;
    const int lane = tid & 63;
    const int w    = tid >> 6;      // 0..7
    const int wm   = w >> 2;        // 0..1
    const int wn   = w & 3;         // 0..3

    // bijective XCD swizzle (m204): nwg = 1036, q=129, r=4
    const int orig = blockIdx.x;
    const int xcd  = orig & 7;
    const int gidx = orig >> 3;
    const int wg   = (xcd < 4 ? xcd * 130 : 520 + (xcd - 4) * 129) + gidx;
    const int panel = wg >> 2;
    const int mblk  = wg & 3;
    const int m0 = mblk * 256;
    const int n0 = panel * 256;

    const ushort* BpP = Bp + (size_t)panel * 262144;   // 512 KB per panel (in ushorts)

    const int u4 = lane >> 4, l15 = lane & 15, l7 = lane & 7, l3h = lane >> 3;
    const int w2 = w & 3, half = w >> 2;
    const int aGuk = (l7 ^ l3h) << 3;   // pre-swizzled k-offset (ushorts) for A staging

    // stage A chunk j of tile tt into buf: rows {32j..32j+31} (waves 0-3) / {128+32j..} (waves 4-7)
    auto stageA = [&](int buf, int tt, int j) {
        const int r0 = half * 128 + 32 * j + 8 * w2;       // wave-uniform segment base row
        const int r  = r0 + l3h;
        const ushort* src = h3 + (((size_t)(m0 + r)) << 10) + tt * 64 + aGuk;
        lds_load16(src, (void*)&Alds[buf][r0 * 64]);       // 8 rows x 128 B, linear dest
    };
    // stage B chunk c (units c*512..c*512+511) of tile tt into buf
    auto stageB = [&](int buf, int tt, int c) {
        const int ub = c * 512 + w * 64;                   // wave-uniform unit base
        const ushort* src = BpP + (((size_t)tt * 2048 + ub + lane) << 3);
        lds_load16(src, (void*)&Blds[buf][ub * 8]);
    };

    f32x4 acc[8][4] = {};

    // ---- prologue: stage tiles 0 and 1 (8+8 loads/thread), wait tile 0 ----
    #pragma unroll
    for (int c = 0; c < 4; ++c) stageB(0, 0, c);
    #pragma unroll
    for (int j = 0; j < 4; ++j) stageA(0, 0, j);
    #pragma unroll
    for (int c = 0; c < 4; ++c) stageB(1, 1, c);
    #pragma unroll
    for (int j = 0; j < 4; ++j) stageA(1, 1, j);
    asm volatile("s_waitcnt vmcnt(8)" ::: "memory");
    __builtin_amdgcn_sched_barrier(0);
    asm volatile("s_barrier" ::: "memory");
    __builtin_amdgcn_sched_barrier(0);

    // ---- main loop: 4 phases per K-tile; vmcnt(6) only at tile boundaries ----
    for (int t = 0; t < NT; ++t) {
        const int buf = t & 1;
        const ushort* Ab = Alds[buf];
        const ushort* Bb = Blds[buf];
        s16x8 bfr[4][2];
        #pragma unroll
        for (int q = 0; q < 4; ++q) {
            // ds-read subtile (phase q needs A m-frags {2q,2q+1}; B read fully at q==0)
            s16x8 af[2][2];
            if (q == 0) {
                #pragma unroll
                for (int fn = 0; fn < 4; ++fn)
                    #pragma unroll
                    for (int ks = 0; ks < 2; ++ks)
                        bfr[fn][ks] = *reinterpret_cast<const s16x8*>(
                            &Bb[(((ks * 4 + u4) << 8) + wn * 64 + l15 + fn * 16) * 8]);
            }
            #pragma unroll
            for (int f = 0; f < 2; ++f)
                #pragma unroll
                for (int ks = 0; ks < 2; ++ks) {
                    const int r  = wm * 128 + (2 * q + f) * 16 + l15;
                    const int cc = (ks * 4 + u4) ^ l7;
                    af[f][ks] = *reinterpret_cast<const s16x8*>(&Ab[(r * 8 + cc) * 8]);
                }
            // stage issues (2 loads/thread/phase), death-stripe-aligned:
            if (q == 0)      { if (t >= 1 && t + 1 < NT) { stageA(buf ^ 1, t + 1, 2); stageA(buf ^ 1, t + 1, 3); } }
            else if (q == 1) { if (t + 2 < NT)           { stageB(buf,     t + 2, 0); stageB(buf,     t + 2, 1); } }
            else if (q == 2) { if (t + 2 < NT)           { stageB(buf,     t + 2, 2); stageB(buf,     t + 2, 3); } }
            else             { if (t + 2 < NT)           { stageA(buf,     t + 2, 0); stageA(buf,     t + 2, 1); } }

            asm volatile("s_barrier" ::: "memory");
            __builtin_amdgcn_sched_barrier(0);
            asm volatile("s_waitcnt lgkmcnt(0)" ::: "memory");
            __builtin_amdgcn_sched_barrier(0);
            __builtin_amdgcn_s_setprio(1);
            #pragma unroll
            for (int f = 0; f < 2; ++f)
                #pragma unroll
                for (int fn = 0; fn < 4; ++fn)
                    #pragma unroll
                    for (int ks = 0; ks < 2; ++ks)
                        acc[2 * q + f][fn] = __builtin_amdgcn_mfma_f32_16x16x32_bf16(
                            af[f][ks], bfr[fn][ks], acc[2 * q + f][fn], 0, 0, 0);
            __builtin_amdgcn_s_setprio(0);
            __builtin_amdgcn_sched_barrier(0);
            if (q == 3) {
                if (t == NT - 2)     { asm volatile("s_waitcnt vmcnt(0)" ::: "memory"); }
                else if (t < NT - 2) { asm volatile("s_waitcnt vmcnt(6)" ::: "memory"); }
                __builtin_amdgcn_sched_barrier(0);
            }
            asm volatile("s_barrier" ::: "memory");
            __builtin_amdgcn_sched_barrier(0);
        }
    }

    // ---- epilogue: sigmoid(acc + b_out); C/D layout col=lane&15, row=(lane>>4)*4+j ----
    const int rb = m0 + wm * 128 + u4 * 4;
    #pragma unroll
    for (int fn = 0; fn < 4; ++fn) {
        const int col = n0 + wn * 64 + fn * 16 + l15;
        if (col < N_OUT) {
            const float bo = bout[col];
            #pragma unroll
            for (int fm = 0; fm < 8; ++fm) {
                #pragma unroll
                for (int j = 0; j < 4; ++j) {
                    const int row = rb + fm * 16 + j;
                    const float z = acc[fm][fn][j] + bo;
                    out[(size_t)row * N_OUT + col] = 1.f / (1.f + __expf(-z));
                }
            }
        }
    }
}

// ---------------- fallback: fused f32->bf16 inside GEMM (128-tile, round-1 kernel) ----------------
__global__ __launch_bounds__(256, 2) void gemm_out_fused(
    const ushort* __restrict__ h3, const float* __restrict__ Wout,
    const float* __restrict__ bout, float* __restrict__ out)
{
    __shared__ __align__(16) ushort Alds[2][128 * 64];
    __shared__ __align__(16) ushort Blds[2][64 * 128];

    const int tid = threadIdx.x;
    const int lane = tid & 63;
    const int w = tid >> 6;
    const int wm = w >> 1, wn = w & 1;

    const int raw = blockIdx.x;
    const int panel = (raw >> 6) * 8 + (raw & 7);
    const int mblk = (raw >> 3) & 7;
    if (panel >= 517) return;
    const int m0 = mblk * 128;
    const int n0 = panel * 128;

    const int nl = tid & 127;
    const int kb0 = tid >> 7;
    int nc = n0 + nl; if (nc > N_OUT - 1) nc = N_OUT - 1;
    const float* Bsrc = Wout + nc;

    f32x4 acc[4][4] = {};
    float breg[32];

    const int arow = wm * 64 + (lane & 15);
    const int ac0  = lane >> 4;
    const int bn   = wn * 64 + (lane & 15);

    auto stageA = [&](int buf, int kt) {
        const int k0 = kt * 64;
        #pragma unroll
        for (int i = 0; i < 4; ++i) {
            const int u = (w * 4 + i) * 64 + lane;
            const int r = u >> 3, cc = u & 7;
            const ushort* src = h3 + (size_t)(m0 + r) * K_DIM + (k0 + ((cc ^ (r & 7)) << 3));
            lds_load16(src, (void*)&Alds[buf][(w * 4 + i) * 512]);
        }
    };
    auto loadB = [&](int kt) {
        const int k0 = kt * 64;
        #pragma unroll
        for (int g = 0; g < 4; ++g) {
            const int kb = kb0 + g * 2;
            #pragma unroll
            for (int i = 0; i < 8; ++i)
                breg[g * 8 + i] = Bsrc[(size_t)(k0 + kb * 8 + i) * N_OUT];
        }
    };
    auto writeB = [&](int buf) {
        #pragma unroll
        for (int g = 0; g < 4; ++g) {
            const int kb = kb0 + g * 2;
            s16x8 v;
            #pragma unroll
            for (int i = 0; i < 8; ++i) v[i] = (short)f2bf(breg[g * 8 + i]);
            *reinterpret_cast<s16x8*>(&Blds[buf][(kb * 128 + nl) * 8]) = v;
        }
    };
    auto compute = [&](int buf) {
        #pragma unroll
        for (int ks = 0; ks < 2; ++ks) {
            s16x8 af[4], bfr[4];
            #pragma unroll
            for (int fm = 0; fm < 4; ++fm) {
                const int r = arow + fm * 16;
                const int cc = (ks * 4 + ac0) ^ (r & 7);
                af[fm] = *reinterpret_cast<const s16x8*>(&Alds[buf][r * 64 + cc * 8]);
            }
            const int kb = ks * 4 + ac0;
            #pragma unroll
            for (int fn = 0; fn < 4; ++fn)
                bfr[fn] = *reinterpret_cast<const s16x8*>(&Blds[buf][(kb * 128 + bn + fn * 16) * 8]);
            #pragma unroll
            for (int fm = 0; fm < 4; ++fm)
                #pragma unroll
                for (int fn = 0; fn < 4; ++fn)
                    acc[fm][fn] = __builtin_amdgcn_mfma_f32_16x16x32_bf16(
                        af[fm], bfr[fn], acc[fm][fn], 0, 0, 0);
        }
    };

    stageA(0, 0);
    loadB(0);
    writeB(0);
    __syncthreads();

    for (int kt = 0; kt < 16; ++kt) {
        const int buf = kt & 1;
        if (kt + 1 < 16) {
            stageA(buf ^ 1, kt + 1);
            loadB(kt + 1);
        }
        compute(buf);
        if (kt + 1 < 16) writeB(buf ^ 1);
        __syncthreads();
    }

    const int rbase = m0 + wm * 64 + (lane >> 4) * 4;
    #pragma unroll
    for (int fn = 0; fn < 4; ++fn) {
        const int col = n0 + wn * 64 + fn * 16 + (lane & 15);
        const bool ok = col < N_OUT;
        const float bo = bout[ok ? col : (N_OUT - 1)];
        #pragma unroll
        for (int fm = 0; fm < 4; ++fm) {
            #pragma unroll
            for (int j = 0; j < 4; ++j) {
                if (ok) {
                    const int row = rbase + fm * 16 + j;
                    const float z = acc[fm][fn][j] + bo;
                    out[(size_t)row * N_OUT + col] = 1.f / (1.f + __expf(-z));
                }
            }
        }
    }
}

extern "C" void kernel_launch(void* const* d_in, const int* in_sizes, int n_in,
                              void* d_out, int out_size, void* d_ws, size_t ws_size,
                              hipStream_t stream)
{
    const float* noise = (const float*)d_in[0];
    const int*   orders = (const int*)d_in[1];
    const float* emb   = (const float*)d_in[2];
    const float* W1 = (const float*)d_in[3];
    const float* b1 = (const float*)d_in[4];
    const float* W2 = (const float*)d_in[5];
    const float* b2 = (const float*)d_in[6];
    const float* W3 = (const float*)d_in[7];
    const float* b3 = (const float*)d_in[8];
    const float* Wout = (const float*)d_in[9];
    const float* bout = (const float*)d_in[10];

    // packed workspace: x overlays h2 (x dead before h2 is written)
    char* ws = (char*)d_ws;
    float*  x  = (float*)(ws);               // [0, 475 KB)   (dead after L1)
    float*  h2 = (float*)(ws);               // [0, 2 MB)     (written by L2, after x is dead)
    float*  h1 = (float*)(ws + 0x200000);    // [2 MB, 3 MB)
    ushort* h3 = (ushort*)(ws + 0x300000);   // [3 MB, 5 MB)  bf16
    ushort* Bp = (ushort*)(ws + 0x500000);   // 259 * 512 KB = 129.5 MiB
    const size_t need = 0x500000 + (size_t)NPANEL * 262144 * 2;

    const bool pre = (ws_size >= need);

    if (pre) convert_wout<<<NPANEL * 128, 256, 0, stream>>>(Wout, Bp);
    build_x<<<464, 256, 0, stream>>>(noise, orders, emb, x);
    gemm_relu<false><<<dim3(16, 4),  256, 0, stream>>>(x,  W1, b1, (void*)h1, 1024, 256,  116);
    gemm_relu<false><<<dim3(16, 8),  256, 0, stream>>>(h1, W2, b2, (void*)h2, 1024, 512,  256);
    gemm_relu<true ><<<dim3(16, 16), 256, 0, stream>>>(h2, W3, b3, (void*)h3, 1024, 1024, 512);
    if (pre)
        gemm_out<<<NPANEL * 4, 512, 0, stream>>>(h3, Bp, bout, (float*)d_out);
    else
        gemm_out_fused<<<4160, 256, 0, stream>>>(h3, Wout, bout, (float*)d_out);
}

// Round 4
// 533.870 us; speedup vs baseline: 1.0627x; 1.0627x over previous
//
#include <hip/hip_runtime.h>

typedef float f32x4 __attribute__((ext_vector_type(4)));
typedef short s16x8 __attribute__((ext_vector_type(8)));

#define N_OUT 66049
#define M_DIM 1024
#define K_DIM 1024
#define NPANEL 517           // ceil(66049/128)

// round-to-nearest-even f32 -> bf16 (finite inputs)
__device__ __forceinline__ ushort f2bf(float f) {
    union { float f; unsigned u; } x; x.f = f;
    unsigned r = x.u + 0x7fffu + ((x.u >> 16) & 1u);
    return (ushort)(r >> 16);
}

// 16B global -> LDS direct (wave-uniform LDS base + lane*16; global addr per-lane)
__device__ __forceinline__ void lds_load16(const void* g, void* l) {
    auto gp = reinterpret_cast<const __attribute__((address_space(1))) char*>(
        reinterpret_cast<uintptr_t>(g));
    auto lp = reinterpret_cast<__attribute__((address_space(3))) char*>(
        reinterpret_cast<uintptr_t>(l));
    __builtin_amdgcn_global_load_lds(gp, lp, 16, 0, 0);
}

// ---------------- x = concat(noise, embed[orders]) : [1024][116] ----------------
__global__ void build_x(const float* __restrict__ noise, const int* __restrict__ orders,
                        const float* __restrict__ emb, float* __restrict__ x)
{
    int idx = blockIdx.x * 256 + threadIdx.x;
    if (idx >= 1024 * 116) return;
    int b = idx / 116, c = idx - b * 116;
    float v = (c < 100) ? noise[b * 100 + c] : emb[orders[b] * 16 + (c - 100)];
    x[idx] = v;
}

// ---------------- small fp32 GEMM: C = relu(A@W + b), 64x64 tile ----------------
template <bool OUT_BF16>
__global__ __launch_bounds__(256) void gemm_relu(
    const float* __restrict__ A, const float* __restrict__ W,
    const float* __restrict__ bias, void* __restrict__ Cout,
    int M, int N, int K)
{
    __shared__ __align__(16) float As[16][68];  // [k][m], padded
    __shared__ __align__(16) float Ws[16][68];  // [k][n], padded
    const int tid = threadIdx.x;
    const int m0 = blockIdx.x * 64, n0 = blockIdx.y * 64;
    const int tr = tid >> 4, tc = tid & 15;
    float acc[4][4] = {};
    for (int k0 = 0; k0 < K; k0 += 16) {
        #pragma unroll
        for (int e = 0; e < 4; ++e) {
            int idx = e * 256 + tid;
            int r = idx >> 4, c = idx & 15;
            As[c][r] = (k0 + c < K) ? A[(size_t)(m0 + r) * K + k0 + c] : 0.f;
            int rw = idx >> 6, cw = idx & 63;
            Ws[rw][cw] = (k0 + rw < K) ? W[(size_t)(k0 + rw) * N + n0 + cw] : 0.f;
        }
        __syncthreads();
        #pragma unroll
        for (int kk = 0; kk < 16; ++kk) {
            f32x4 a = *reinterpret_cast<const f32x4*>(&As[kk][tr * 4]);
            f32x4 b = *reinterpret_cast<const f32x4*>(&Ws[kk][tc * 4]);
            #pragma unroll
            for (int i = 0; i < 4; ++i)
                #pragma unroll
                for (int j = 0; j < 4; ++j)
                    acc[i][j] = fmaf(a[i], b[j], acc[i][j]);
        }
        __syncthreads();
    }
    f32x4 bo = *reinterpret_cast<const f32x4*>(&bias[n0 + tc * 4]);
    #pragma unroll
    for (int i = 0; i < 4; ++i) {
        int m = m0 + tr * 4 + i;
        if (OUT_BF16) {
            ushort4 u;
            u.x = f2bf(fmaxf(acc[i][0] + bo[0], 0.f));
            u.y = f2bf(fmaxf(acc[i][1] + bo[1], 0.f));
            u.z = f2bf(fmaxf(acc[i][2] + bo[2], 0.f));
            u.w = f2bf(fmaxf(acc[i][3] + bo[3], 0.f));
            *reinterpret_cast<ushort4*>(&((ushort*)Cout)[(size_t)m * N + n0 + tc * 4]) = u;
        } else {
            f32x4 v;
            #pragma unroll
            for (int j = 0; j < 4; ++j) v[j] = fmaxf(acc[i][j] + bo[j], 0.f);
            *reinterpret_cast<f32x4*>(&((float*)Cout)[(size_t)m * N + n0 + tc * 4]) = v;
        }
    }
}

// ------- convert W_out (f32 [K][N]) -> Bp (bf16, [panel128][kb(128)][nl(128)][kj8]) -------
// LDS-transpose version: block (p, kt) reads a 64x128 f32 tile coalesced (512 B row
// segments), transposes via padded LDS, writes its 16 KB Bp chunk contiguously.
__global__ __launch_bounds__(256) void convert_wout(
    const float* __restrict__ Wout, ushort* __restrict__ Bp)
{
    __shared__ float T[64][132];                  // +4 pad: 2-way-free reads
    const int bid = blockIdx.x;                   // p*16 + kt
    const int p  = bid >> 4;
    const int kt = bid & 15;
    const int tid = threadIdx.x;
    const int k0 = kt * 64;

    if (p < NPANEL - 1) {
        const int c4 = (tid & 31) * 4;            // col offset within panel
        const int r0 = tid >> 5;                  // 0..7
        const float* src = Wout + (size_t)k0 * N_OUT + (size_t)p * 128 + c4;
        #pragma unroll
        for (int i = 0; i < 8; ++i) {
            const int r = r0 + i * 8;
            f32x4 v = *reinterpret_cast<const f32x4*>(src + (size_t)r * N_OUT);
            *reinterpret_cast<f32x4*>(&T[r][c4]) = v;
        }
    } else {
        // last panel (only col 66048 valid): scalar, col-clamped (no OOB reads)
        const int c = tid & 31, r0 = tid >> 5;
        #pragma unroll
        for (int i = 0; i < 8; ++i) {
            const int r = r0 + i * 8;
            #pragma unroll
            for (int j = 0; j < 4; ++j) {
                int col = p * 128 + c * 4 + j;
                if (col > N_OUT - 1) col = N_OUT - 1;
                T[r][c * 4 + j] = Wout[(size_t)(k0 + r) * N_OUT + col];
            }
        }
    }
    __syncthreads();

    const size_t base = ((size_t)p * 128 + kt * 8) * 128 * 8;   // ushort index
    #pragma unroll
    for (int i = 0; i < 4; ++i) {
        const int v = tid + i * 256;
        const int kbl = v >> 7, nl = v & 127;
        s16x8 o;
        #pragma unroll
        for (int j = 0; j < 8; ++j) o[j] = (short)f2bf(T[kbl * 8 + j][nl]);
        *reinterpret_cast<s16x8*>(Bp + base + (size_t)v * 8) = o;
    }
}

// ---------------- big GEMM: out = sigmoid(h3(bf16) @ Bp(bf16) + bout) ----------------
// m97 structure: 128x128 tile, BK=64, 4 waves (2x2), single-buffer LDS, 2 barriers/K-step.
// launch_bounds(256,4): 4 blocks/CU (VGPR 60 + AGPR 64 = 124 <= 128 unified; LDS 4x32KB).
__global__ __launch_bounds__(256, 4) void gemm_out(
    const ushort* __restrict__ h3, const ushort* __restrict__ Bp,
    const float* __restrict__ bout, float* __restrict__ out)
{
    // A: [row r][16B-unit cc], cc XOR-swizzled by (r&7): LDS[r][cc] = global[r][cc^(r&7)]
    __shared__ __align__(16) ushort Alds[128 * 64];
    // B: [kbl(8)][nl(128)][kj(8)] — matches Bp global layout (linear copy)
    __shared__ __align__(16) ushort Blds[64 * 128];

    const int tid = threadIdx.x;
    const int lane = tid & 63;
    const int w = tid >> 6;
    const int wm = w >> 1, wn = w & 1;

    // XCD-grouped mapping: 8 m-blocks of a panel land on one XCD (B panel L2 reuse)
    const int raw = blockIdx.x;
    const int panel = (raw >> 6) * 8 + (raw & 7);
    const int mblk = (raw >> 3) & 7;
    if (panel >= NPANEL) return;
    const int m0 = mblk * 128;
    const int n0 = panel * 128;

    f32x4 acc[4][4] = {};

    const int arow = wm * 64 + (lane & 15);  // + fm*16
    const int ac0  = lane >> 4;
    const int bn   = wn * 64 + (lane & 15);  // + fn*16

    const ushort* BpPanel = Bp + (size_t)panel * (128 * 128 * 8);

    for (int kt = 0; kt < 16; ++kt) {
        const int k0 = kt * 64;
        // ---- stage A (16 KB) : 4 global_load_lds per thread, swizzled source ----
        #pragma unroll
        for (int i = 0; i < 4; ++i) {
            const int u = (w * 4 + i) * 64 + lane;       // linear 16B unit
            const int r = u >> 3, cc = u & 7;
            const ushort* src = h3 + (size_t)(m0 + r) * K_DIM + (k0 + ((cc ^ (r & 7)) << 3));
            lds_load16(src, (void*)&Alds[(w * 4 + i) * 512]);
        }
        // ---- stage B (16 KB) : contiguous chunk, linear copy ----
        const ushort* bsrc = BpPanel + (size_t)kt * 8192;
        #pragma unroll
        for (int i = 0; i < 4; ++i) {
            const int u = (w * 4 + i) * 64 + lane;
            lds_load16(bsrc + (size_t)u * 8, (void*)&Blds[(w * 4 + i) * 512]);
        }
        __syncthreads();   // compiler drains vmcnt(0) here

        // ---- compute: 16 ds_read_b128 + 32 MFMA per thread ----
        #pragma unroll
        for (int ks = 0; ks < 2; ++ks) {
            s16x8 af[4], bfr[4];
            #pragma unroll
            for (int fm = 0; fm < 4; ++fm) {
                const int r = arow + fm * 16;
                const int cc = (ks * 4 + ac0) ^ (r & 7);
                af[fm] = *reinterpret_cast<const s16x8*>(&Alds[r * 64 + cc * 8]);
            }
            const int kbl = ks * 4 + ac0;
            #pragma unroll
            for (int fn = 0; fn < 4; ++fn)
                bfr[fn] = *reinterpret_cast<const s16x8*>(&Blds[(kbl * 128 + bn + fn * 16) * 8]);
            #pragma unroll
            for (int fm = 0; fm < 4; ++fm)
                #pragma unroll
                for (int fn = 0; fn < 4; ++fn)
                    acc[fm][fn] = __builtin_amdgcn_mfma_f32_16x16x32_bf16(
                        af[fm], bfr[fn], acc[fm][fn], 0, 0, 0);
        }
        __syncthreads();
    }

    // epilogue: sigmoid(acc + b_out); C/D layout col=lane&15, row=(lane>>4)*4+j
    const int rbase = m0 + wm * 64 + (lane >> 4) * 4;
    #pragma unroll
    for (int fn = 0; fn < 4; ++fn) {
        const int col = n0 + wn * 64 + fn * 16 + (lane & 15);
        const bool ok = col < N_OUT;
        const float bo = bout[ok ? col : (N_OUT - 1)];
        #pragma unroll
        for (int fm = 0; fm < 4; ++fm) {
            #pragma unroll
            for (int j = 0; j < 4; ++j) {
                if (ok) {
                    const int row = rbase + fm * 16 + j;
                    const float z = acc[fm][fn][j] + bo;
                    out[(size_t)row * N_OUT + col] = 1.f / (1.f + __expf(-z));
                }
            }
        }
    }
}

// ---------------- fallback: fused f32->bf16 inside GEMM (round-1 kernel) ----------------
__global__ __launch_bounds__(256, 2) void gemm_out_fused(
    const ushort* __restrict__ h3, const float* __restrict__ Wout,
    const float* __restrict__ bout, float* __restrict__ out)
{
    __shared__ __align__(16) ushort Alds[2][128 * 64];
    __shared__ __align__(16) ushort Blds[2][64 * 128];

    const int tid = threadIdx.x;
    const int lane = tid & 63;
    const int w = tid >> 6;
    const int wm = w >> 1, wn = w & 1;

    const int raw = blockIdx.x;
    const int panel = (raw >> 6) * 8 + (raw & 7);
    const int mblk = (raw >> 3) & 7;
    if (panel >= NPANEL) return;
    const int m0 = mblk * 128;
    const int n0 = panel * 128;

    const int nl = tid & 127;
    const int kb0 = tid >> 7;
    int nc = n0 + nl; if (nc > N_OUT - 1) nc = N_OUT - 1;
    const float* Bsrc = Wout + nc;

    f32x4 acc[4][4] = {};
    float breg[32];

    const int arow = wm * 64 + (lane & 15);
    const int ac0  = lane >> 4;
    const int bn   = wn * 64 + (lane & 15);

    auto stageA = [&](int buf, int kt) {
        const int k0 = kt * 64;
        #pragma unroll
        for (int i = 0; i < 4; ++i) {
            const int u = (w * 4 + i) * 64 + lane;
            const int r = u >> 3, cc = u & 7;
            const ushort* src = h3 + (size_t)(m0 + r) * K_DIM + (k0 + ((cc ^ (r & 7)) << 3));
            lds_load16(src, (void*)&Alds[buf][(w * 4 + i) * 512]);
        }
    };
    auto loadB = [&](int kt) {
        const int k0 = kt * 64;
        #pragma unroll
        for (int g = 0; g < 4; ++g) {
            const int kb = kb0 + g * 2;
            #pragma unroll
            for (int i = 0; i < 8; ++i)
                breg[g * 8 + i] = Bsrc[(size_t)(k0 + kb * 8 + i) * N_OUT];
        }
    };
    auto writeB = [&](int buf) {
        #pragma unroll
        for (int g = 0; g < 4; ++g) {
            const int kb = kb0 + g * 2;
            s16x8 v;
            #pragma unroll
            for (int i = 0; i < 8; ++i) v[i] = (short)f2bf(breg[g * 8 + i]);
            *reinterpret_cast<s16x8*>(&Blds[buf][(kb * 128 + nl) * 8]) = v;
        }
    };
    auto compute = [&](int buf) {
        #pragma unroll
        for (int ks = 0; ks < 2; ++ks) {
            s16x8 af[4], bfr[4];
            #pragma unroll
            for (int fm = 0; fm < 4; ++fm) {
                const int r = arow + fm * 16;
                const int cc = (ks * 4 + ac0) ^ (r & 7);
                af[fm] = *reinterpret_cast<const s16x8*>(&Alds[buf][r * 64 + cc * 8]);
            }
            const int kb = ks * 4 + ac0;
            #pragma unroll
            for (int fn = 0; fn < 4; ++fn)
                bfr[fn] = *reinterpret_cast<const s16x8*>(&Blds[buf][(kb * 128 + bn + fn * 16) * 8]);
            #pragma unroll
            for (int fm = 0; fm < 4; ++fm)
                #pragma unroll
                for (int fn = 0; fn < 4; ++fn)
                    acc[fm][fn] = __builtin_amdgcn_mfma_f32_16x16x32_bf16(
                        af[fm], bfr[fn], acc[fm][fn], 0, 0, 0);
        }
    };

    stageA(0, 0);
    loadB(0);
    writeB(0);
    __syncthreads();

    for (int kt = 0; kt < 16; ++kt) {
        const int buf = kt & 1;
        if (kt + 1 < 16) {
            stageA(buf ^ 1, kt + 1);
            loadB(kt + 1);
        }
        compute(buf);
        if (kt + 1 < 16) writeB(buf ^ 1);
        __syncthreads();
    }

    const int rbase = m0 + wm * 64 + (lane >> 4) * 4;
    #pragma unroll
    for (int fn = 0; fn < 4; ++fn) {
        const int col = n0 + wn * 64 + fn * 16 + (lane & 15);
        const bool ok = col < N_OUT;
        const float bo = bout[ok ? col : (N_OUT - 1)];
        #pragma unroll
        for (int fm = 0; fm < 4; ++fm) {
            #pragma unroll
            for (int j = 0; j < 4; ++j) {
                if (ok) {
                    const int row = rbase + fm * 16 + j;
                    const float z = acc[fm][fn][j] + bo;
                    out[(size_t)row * N_OUT + col] = 1.f / (1.f + __expf(-z));
                }
            }
        }
    }
}

extern "C" void kernel_launch(void* const* d_in, const int* in_sizes, int n_in,
                              void* d_out, int out_size, void* d_ws, size_t ws_size,
                              hipStream_t stream)
{
    const float* noise = (const float*)d_in[0];
    const int*   orders = (const int*)d_in[1];
    const float* emb   = (const float*)d_in[2];
    const float* W1 = (const float*)d_in[3];
    const float* b1 = (const float*)d_in[4];
    const float* W2 = (const float*)d_in[5];
    const float* b2 = (const float*)d_in[6];
    const float* W3 = (const float*)d_in[7];
    const float* b3 = (const float*)d_in[8];
    const float* Wout = (const float*)d_in[9];
    const float* bout = (const float*)d_in[10];

    char* ws = (char*)d_ws;
    float*  x  = (float*)(ws);               // 1024*116*4 = 475 KB
    float*  h1 = (float*)(ws + 0x80000);     // 1 MB
    float*  h2 = (float*)(ws + 0x180000);    // 2 MB
    ushort* h3 = (ushort*)(ws + 0x380000);   // 2 MB (bf16)
    ushort* Bp = (ushort*)(ws + 0x580000);   // 517*128*128*8*2 = 135.5 MB
    const size_t need = 0x580000 + (size_t)NPANEL * 128 * 128 * 8 * 2;

    const bool pre = (ws_size >= need);

    if (pre) convert_wout<<<NPANEL * 16, 256, 0, stream>>>(Wout, Bp);
    build_x<<<464, 256, 0, stream>>>(noise, orders, emb, x);
    gemm_relu<false><<<dim3(16, 4),  256, 0, stream>>>(x,  W1, b1, (void*)h1, 1024, 256,  116);
    gemm_relu<false><<<dim3(16, 8),  256, 0, stream>>>(h1, W2, b2, (void*)h2, 1024, 512,  256);
    gemm_relu<true ><<<dim3(16, 16), 256, 0, stream>>>(h2, W3, b3, (void*)h3, 1024, 1024, 512);
    if (pre)
        gemm_out<<<4160, 256, 0, stream>>>(h3, Bp, bout, (float*)d_out);
    else
        gemm_out_fused<<<4160, 256, 0, stream>>>(h3, Wout, bout, (float*)d_out);
}

// Round 5
// 517.261 us; speedup vs baseline: 1.0968x; 1.0321x over previous
//
#include <hip/hip_runtime.h>

typedef float f32x4 __attribute__((ext_vector_type(4)));
typedef short s16x8 __attribute__((ext_vector_type(8)));

#define N_OUT 66049
#define M_DIM 1024
#define K_DIM 1024
#define NPANEL 517           // ceil(66049/128)

// round-to-nearest-even f32 -> bf16 (finite inputs)
__device__ __forceinline__ ushort f2bf(float f) {
    union { float f; unsigned u; } x; x.f = f;
    unsigned r = x.u + 0x7fffu + ((x.u >> 16) & 1u);
    return (ushort)(r >> 16);
}

// 16B global -> LDS direct (wave-uniform LDS base + lane*16; global addr per-lane)
__device__ __forceinline__ void lds_load16(const void* g, void* l) {
    auto gp = reinterpret_cast<const __attribute__((address_space(1))) char*>(
        reinterpret_cast<uintptr_t>(g));
    auto lp = reinterpret_cast<__attribute__((address_space(3))) char*>(
        reinterpret_cast<uintptr_t>(l));
    __builtin_amdgcn_global_load_lds(gp, lp, 16, 0, 0);
}

// ---------------- x = concat(noise, embed[orders]) : [1024][116] ----------------
__global__ void build_x(const float* __restrict__ noise, const int* __restrict__ orders,
                        const float* __restrict__ emb, float* __restrict__ x)
{
    int idx = blockIdx.x * 256 + threadIdx.x;
    if (idx >= 1024 * 116) return;
    int b = idx / 116, c = idx - b * 116;
    float v = (c < 100) ? noise[b * 100 + c] : emb[orders[b] * 16 + (c - 100)];
    x[idx] = v;
}

// ---------------- small fp32 GEMM: C = relu(A@W + b), 64x64 tile ----------------
template <bool OUT_BF16>
__global__ __launch_bounds__(256) void gemm_relu(
    const float* __restrict__ A, const float* __restrict__ W,
    const float* __restrict__ bias, void* __restrict__ Cout,
    int M, int N, int K)
{
    __shared__ __align__(16) float As[16][68];  // [k][m], padded
    __shared__ __align__(16) float Ws[16][68];  // [k][n], padded
    const int tid = threadIdx.x;
    const int m0 = blockIdx.x * 64, n0 = blockIdx.y * 64;
    const int tr = tid >> 4, tc = tid & 15;
    float acc[4][4] = {};
    for (int k0 = 0; k0 < K; k0 += 16) {
        #pragma unroll
        for (int e = 0; e < 4; ++e) {
            int idx = e * 256 + tid;
            int r = idx >> 4, c = idx & 15;
            As[c][r] = (k0 + c < K) ? A[(size_t)(m0 + r) * K + k0 + c] : 0.f;
            int rw = idx >> 6, cw = idx & 63;
            Ws[rw][cw] = (k0 + rw < K) ? W[(size_t)(k0 + rw) * N + n0 + cw] : 0.f;
        }
        __syncthreads();
        #pragma unroll
        for (int kk = 0; kk < 16; ++kk) {
            f32x4 a = *reinterpret_cast<const f32x4*>(&As[kk][tr * 4]);
            f32x4 b = *reinterpret_cast<const f32x4*>(&Ws[kk][tc * 4]);
            #pragma unroll
            for (int i = 0; i < 4; ++i)
                #pragma unroll
                for (int j = 0; j < 4; ++j)
                    acc[i][j] = fmaf(a[i], b[j], acc[i][j]);
        }
        __syncthreads();
    }
    f32x4 bo = *reinterpret_cast<const f32x4*>(&bias[n0 + tc * 4]);
    #pragma unroll
    for (int i = 0; i < 4; ++i) {
        int m = m0 + tr * 4 + i;
        if (OUT_BF16) {
            ushort4 u;
            u.x = f2bf(fmaxf(acc[i][0] + bo[0], 0.f));
            u.y = f2bf(fmaxf(acc[i][1] + bo[1], 0.f));
            u.z = f2bf(fmaxf(acc[i][2] + bo[2], 0.f));
            u.w = f2bf(fmaxf(acc[i][3] + bo[3], 0.f));
            *reinterpret_cast<ushort4*>(&((ushort*)Cout)[(size_t)m * N + n0 + tc * 4]) = u;
        } else {
            f32x4 v;
            #pragma unroll
            for (int j = 0; j < 4; ++j) v[j] = fmaxf(acc[i][j] + bo[j], 0.f);
            *reinterpret_cast<f32x4*>(&((float*)Cout)[(size_t)m * N + n0 + tc * 4]) = v;
        }
    }
}

// ------- convert W_out (f32 [K][N]) -> Bp (bf16, [panel128][kb(128)][nl(128)][kj8]) -------
// LDS-transpose, ROW-BAND-MAJOR dispatch: blockIdx.x = panel (fast), blockIdx.y = kt (slow).
// Consecutive blocks read the SAME 64-row band at consecutive 512 B column slabs -> each
// DRAM page is consumed sequentially instead of 512 B per activation (round-4 was
// panel-major: every 512 B read opened a fresh page at 264 KB stride -> ~2.4 TB/s).
__global__ __launch_bounds__(256) void convert_wout(
    const float* __restrict__ Wout, ushort* __restrict__ Bp)
{
    __shared__ float T[64][132];                  // +4 pad: conflict-free transpose reads
    const int p  = blockIdx.x;                    // panel (fast dim)
    const int kt = blockIdx.y;                    // 64-row band (slow dim)
    const int tid = threadIdx.x;
    const int k0 = kt * 64;

    if (p < NPANEL - 1) {
        const int c4 = (tid & 31) * 4;            // col offset within panel
        const int r0 = tid >> 5;                  // 0..7
        const float* src = Wout + (size_t)k0 * N_OUT + (size_t)p * 128 + c4;
        #pragma unroll
        for (int i = 0; i < 8; ++i) {
            const int r = r0 + i * 8;
            f32x4 v = *reinterpret_cast<const f32x4*>(src + (size_t)r * N_OUT);
            *reinterpret_cast<f32x4*>(&T[r][c4]) = v;
        }
    } else {
        // last panel (only col 66048 valid): scalar, col-clamped (no OOB reads)
        const int c = tid & 31, r0 = tid >> 5;
        #pragma unroll
        for (int i = 0; i < 8; ++i) {
            const int r = r0 + i * 8;
            #pragma unroll
            for (int j = 0; j < 4; ++j) {
                int col = p * 128 + c * 4 + j;
                if (col > N_OUT - 1) col = N_OUT - 1;
                T[r][c * 4 + j] = Wout[(size_t)(k0 + r) * N_OUT + col];
            }
        }
    }
    __syncthreads();

    const size_t base = ((size_t)p * 128 + kt * 8) * 128 * 8;   // ushort index
    #pragma unroll
    for (int i = 0; i < 4; ++i) {
        const int v = tid + i * 256;
        const int kbl = v >> 7, nl = v & 127;
        s16x8 o;
        #pragma unroll
        for (int j = 0; j < 8; ++j) o[j] = (short)f2bf(T[kbl * 8 + j][nl]);
        *reinterpret_cast<s16x8*>(Bp + base + (size_t)v * 8) = o;
    }
}

// ---------------- big GEMM: out = sigmoid(h3(bf16) @ Bp(bf16) + bout) ----------------
// m97 structure: 128x128 tile, BK=64, 4 waves (2x2), single-buffer LDS, 2 barriers/K-step.
__global__ __launch_bounds__(256, 4) void gemm_out(
    const ushort* __restrict__ h3, const ushort* __restrict__ Bp,
    const float* __restrict__ bout, float* __restrict__ out)
{
    // A: [row r][16B-unit cc], cc XOR-swizzled by (r&7): LDS[r][cc] = global[r][cc^(r&7)]
    __shared__ __align__(16) ushort Alds[128 * 64];
    // B: [kbl(8)][nl(128)][kj(8)] — matches Bp global layout (linear copy)
    __shared__ __align__(16) ushort Blds[64 * 128];

    const int tid = threadIdx.x;
    const int lane = tid & 63;
    const int w = tid >> 6;
    const int wm = w >> 1, wn = w & 1;

    // XCD-grouped mapping: 8 m-blocks of a panel land on one XCD (B panel L2 reuse)
    const int raw = blockIdx.x;
    const int panel = (raw >> 6) * 8 + (raw & 7);
    const int mblk = (raw >> 3) & 7;
    if (panel >= NPANEL) return;
    const int m0 = mblk * 128;
    const int n0 = panel * 128;

    f32x4 acc[4][4] = {};

    const int arow = wm * 64 + (lane & 15);  // + fm*16
    const int ac0  = lane >> 4;
    const int bn   = wn * 64 + (lane & 15);  // + fn*16

    const ushort* BpPanel = Bp + (size_t)panel * (128 * 128 * 8);

    for (int kt = 0; kt < 16; ++kt) {
        const int k0 = kt * 64;
        // ---- stage A (16 KB) : 4 global_load_lds per thread, swizzled source ----
        #pragma unroll
        for (int i = 0; i < 4; ++i) {
            const int u = (w * 4 + i) * 64 + lane;       // linear 16B unit
            const int r = u >> 3, cc = u & 7;
            const ushort* src = h3 + (size_t)(m0 + r) * K_DIM + (k0 + ((cc ^ (r & 7)) << 3));
            lds_load16(src, (void*)&Alds[(w * 4 + i) * 512]);
        }
        // ---- stage B (16 KB) : contiguous chunk, linear copy ----
        const ushort* bsrc = BpPanel + (size_t)kt * 8192;
        #pragma unroll
        for (int i = 0; i < 4; ++i) {
            const int u = (w * 4 + i) * 64 + lane;
            lds_load16(bsrc + (size_t)u * 8, (void*)&Blds[(w * 4 + i) * 512]);
        }
        __syncthreads();   // compiler drains vmcnt(0) here

        // ---- compute: 16 ds_read_b128 + 32 MFMA per thread ----
        #pragma unroll
        for (int ks = 0; ks < 2; ++ks) {
            s16x8 af[4], bfr[4];
            #pragma unroll
            for (int fm = 0; fm < 4; ++fm) {
                const int r = arow + fm * 16;
                const int cc = (ks * 4 + ac0) ^ (r & 7);
                af[fm] = *reinterpret_cast<const s16x8*>(&Alds[r * 64 + cc * 8]);
            }
            const int kbl = ks * 4 + ac0;
            #pragma unroll
            for (int fn = 0; fn < 4; ++fn)
                bfr[fn] = *reinterpret_cast<const s16x8*>(&Blds[(kbl * 128 + bn + fn * 16) * 8]);
            #pragma unroll
            for (int fm = 0; fm < 4; ++fm)
                #pragma unroll
                for (int fn = 0; fn < 4; ++fn)
                    acc[fm][fn] = __builtin_amdgcn_mfma_f32_16x16x32_bf16(
                        af[fm], bfr[fn], acc[fm][fn], 0, 0, 0);
        }
        __syncthreads();
    }

    // epilogue: sigmoid(acc + b_out); C/D layout col=lane&15, row=(lane>>4)*4+j
    const int rbase = m0 + wm * 64 + (lane >> 4) * 4;
    #pragma unroll
    for (int fn = 0; fn < 4; ++fn) {
        const int col = n0 + wn * 64 + fn * 16 + (lane & 15);
        const bool ok = col < N_OUT;
        const float bo = bout[ok ? col : (N_OUT - 1)];
        #pragma unroll
        for (int fm = 0; fm < 4; ++fm) {
            #pragma unroll
            for (int j = 0; j < 4; ++j) {
                if (ok) {
                    const int row = rbase + fm * 16 + j;
                    const float z = acc[fm][fn][j] + bo;
                    out[(size_t)row * N_OUT + col] = 1.f / (1.f + __expf(-z));
                }
            }
        }
    }
}

// ---------------- fallback: fused f32->bf16 inside GEMM (round-1 kernel) ----------------
__global__ __launch_bounds__(256, 2) void gemm_out_fused(
    const ushort* __restrict__ h3, const float* __restrict__ Wout,
    const float* __restrict__ bout, float* __restrict__ out)
{
    __shared__ __align__(16) ushort Alds[2][128 * 64];
    __shared__ __align__(16) ushort Blds[2][64 * 128];

    const int tid = threadIdx.x;
    const int lane = tid & 63;
    const int w = tid >> 6;
    const int wm = w >> 1, wn = w & 1;

    const int raw = blockIdx.x;
    const int panel = (raw >> 6) * 8 + (raw & 7);
    const int mblk = (raw >> 3) & 7;
    if (panel >= NPANEL) return;
    const int m0 = mblk * 128;
    const int n0 = panel * 128;

    const int nl = tid & 127;
    const int kb0 = tid >> 7;
    int nc = n0 + nl; if (nc > N_OUT - 1) nc = N_OUT - 1;
    const float* Bsrc = Wout + nc;

    f32x4 acc[4][4] = {};
    float breg[32];

    const int arow = wm * 64 + (lane & 15);
    const int ac0  = lane >> 4;
    const int bn   = wn * 64 + (lane & 15);

    auto stageA = [&](int buf, int kt) {
        const int k0 = kt * 64;
        #pragma unroll
        for (int i = 0; i < 4; ++i) {
            const int u = (w * 4 + i) * 64 + lane;
            const int r = u >> 3, cc = u & 7;
            const ushort* src = h3 + (size_t)(m0 + r) * K_DIM + (k0 + ((cc ^ (r & 7)) << 3));
            lds_load16(src, (void*)&Alds[buf][(w * 4 + i) * 512]);
        }
    };
    auto loadB = [&](int kt) {
        const int k0 = kt * 64;
        #pragma unroll
        for (int g = 0; g < 4; ++g) {
            const int kb = kb0 + g * 2;
            #pragma unroll
            for (int i = 0; i < 8; ++i)
                breg[g * 8 + i] = Bsrc[(size_t)(k0 + kb * 8 + i) * N_OUT];
        }
    };
    auto writeB = [&](int buf) {
        #pragma unroll
        for (int g = 0; g < 4; ++g) {
            const int kb = kb0 + g * 2;
            s16x8 v;
            #pragma unroll
            for (int i = 0; i < 8; ++i) v[i] = (short)f2bf(breg[g * 8 + i]);
            *reinterpret_cast<s16x8*>(&Blds[buf][(kb * 128 + nl) * 8]) = v;
        }
    };
    auto compute = [&](int buf) {
        #pragma unroll
        for (int ks = 0; ks < 2; ++ks) {
            s16x8 af[4], bfr[4];
            #pragma unroll
            for (int fm = 0; fm < 4; ++fm) {
                const int r = arow + fm * 16;
                const int cc = (ks * 4 + ac0) ^ (r & 7);
                af[fm] = *reinterpret_cast<const s16x8*>(&Alds[buf][r * 64 + cc * 8]);
            }
            const int kb = ks * 4 + ac0;
            #pragma unroll
            for (int fn = 0; fn < 4; ++fn)
                bfr[fn] = *reinterpret_cast<const s16x8*>(&Blds[buf][(kb * 128 + bn + fn * 16) * 8]);
            #pragma unroll
            for (int fm = 0; fm < 4; ++fm)
                #pragma unroll
                for (int fn = 0; fn < 4; ++fn)
                    acc[fm][fn] = __builtin_amdgcn_mfma_f32_16x16x32_bf16(
                        af[fm], bfr[fn], acc[fm][fn], 0, 0, 0);
        }
    };

    stageA(0, 0);
    loadB(0);
    writeB(0);
    __syncthreads();

    for (int kt = 0; kt < 16; ++kt) {
        const int buf = kt & 1;
        if (kt + 1 < 16) {
            stageA(buf ^ 1, kt + 1);
            loadB(kt + 1);
        }
        compute(buf);
        if (kt + 1 < 16) writeB(buf ^ 1);
        __syncthreads();
    }

    const int rbase = m0 + wm * 64 + (lane >> 4) * 4;
    #pragma unroll
    for (int fn = 0; fn < 4; ++fn) {
        const int col = n0 + wn * 64 + fn * 16 + (lane & 15);
        const bool ok = col < N_OUT;
        const float bo = bout[ok ? col : (N_OUT - 1)];
        #pragma unroll
        for (int fm = 0; fm < 4; ++fm) {
            #pragma unroll
            for (int j = 0; j < 4; ++j) {
                if (ok) {
                    const int row = rbase + fm * 16 + j;
                    const float z = acc[fm][fn][j] + bo;
                    out[(size_t)row * N_OUT + col] = 1.f / (1.f + __expf(-z));
                }
            }
        }
    }
}

extern "C" void kernel_launch(void* const* d_in, const int* in_sizes, int n_in,
                              void* d_out, int out_size, void* d_ws, size_t ws_size,
                              hipStream_t stream)
{
    const float* noise = (const float*)d_in[0];
    const int*   orders = (const int*)d_in[1];
    const float* emb   = (const float*)d_in[2];
    const float* W1 = (const float*)d_in[3];
    const float* b1 = (const float*)d_in[4];
    const float* W2 = (const float*)d_in[5];
    const float* b2 = (const float*)d_in[6];
    const float* W3 = (const float*)d_in[7];
    const float* b3 = (const float*)d_in[8];
    const float* Wout = (const float*)d_in[9];
    const float* bout = (const float*)d_in[10];

    char* ws = (char*)d_ws;
    float*  x  = (float*)(ws);               // 1024*116*4 = 475 KB
    float*  h1 = (float*)(ws + 0x80000);     // 1 MB
    float*  h2 = (float*)(ws + 0x180000);    // 2 MB
    ushort* h3 = (ushort*)(ws + 0x380000);   // 2 MB (bf16)
    ushort* Bp = (ushort*)(ws + 0x580000);   // 517*128*128*8*2 = 135.5 MB
    const size_t need = 0x580000 + (size_t)NPANEL * 128 * 128 * 8 * 2;

    const bool pre = (ws_size >= need);

    if (pre) convert_wout<<<dim3(NPANEL, 16), 256, 0, stream>>>(Wout, Bp);
    build_x<<<464, 256, 0, stream>>>(noise, orders, emb, x);
    gemm_relu<false><<<dim3(16, 4),  256, 0, stream>>>(x,  W1, b1, (void*)h1, 1024, 256,  116);
    gemm_relu<false><<<dim3(16, 8),  256, 0, stream>>>(h1, W2, b2, (void*)h2, 1024, 512,  256);
    gemm_relu<true ><<<dim3(16, 16), 256, 0, stream>>>(h2, W3, b3, (void*)h3, 1024, 1024, 512);
    if (pre)
        gemm_out<<<4160, 256, 0, stream>>>(h3, Bp, bout, (float*)d_out);
    else
        gemm_out_fused<<<4160, 256, 0, stream>>>(h3, Wout, bout, (float*)d_out);
}

// Round 6
// 412.114 us; speedup vs baseline: 1.3766x; 1.2551x over previous
//
#include <hip/hip_runtime.h>

typedef float f32x4 __attribute__((ext_vector_type(4)));
typedef short s16x8 __attribute__((ext_vector_type(8)));

#define N_OUT 66049
#define M_DIM 1024
#define K_DIM 1024
#define NPANEL 517           // ceil(66049/128)
#define CONV_BLOCKS_PER_STAGE (NPANEL * 4)   // 4 kt-bands per stage

// round-to-nearest-even f32 -> bf16 (finite inputs)
__device__ __forceinline__ ushort f2bf(float f) {
    union { float f; unsigned u; } x; x.f = f;
    unsigned r = x.u + 0x7fffu + ((x.u >> 16) & 1u);
    return (ushort)(r >> 16);
}

// 16B global -> LDS direct (wave-uniform LDS base + lane*16; global addr per-lane)
__device__ __forceinline__ void lds_load16(const void* g, void* l) {
    auto gp = reinterpret_cast<const __attribute__((address_space(1))) char*>(
        reinterpret_cast<uintptr_t>(g));
    auto lp = reinterpret_cast<__attribute__((address_space(3))) char*>(
        reinterpret_cast<uintptr_t>(l));
    __builtin_amdgcn_global_load_lds(gp, lp, 16, 0, 0);
}

// ---------------- chain bodies (called from fused_stage) ----------------

__device__ __forceinline__ void build_x_body(
    int bid, int tid, const float* __restrict__ noise, const int* __restrict__ orders,
    const float* __restrict__ emb, float* __restrict__ x)
{
    int idx = bid * 256 + tid;
    if (idx >= 1024 * 116) return;
    int b = idx / 116, c = idx - b * 116;
    float v = (c < 100) ? noise[b * 100 + c] : emb[orders[b] * 16 + (c - 100)];
    x[idx] = v;
}

// small fp32 GEMM: C = relu(A@W + b), 64x64 tile; smem >= 8704 B
template <bool OUT_BF16>
__device__ __forceinline__ void gemm_relu_body(
    int bid, int tid, char* smem,
    const float* __restrict__ A, const float* __restrict__ W,
    const float* __restrict__ bias, void* __restrict__ Cout,
    int M, int N, int K)
{
    float* As = (float*)smem;             // [16][68]
    float* Ws = (float*)(smem + 4352);    // [16][68]
    const int m0 = (bid & 15) * 64, n0 = (bid >> 4) * 64;
    const int tr = tid >> 4, tc = tid & 15;
    float acc[4][4] = {};
    for (int k0 = 0; k0 < K; k0 += 16) {
        #pragma unroll
        for (int e = 0; e < 4; ++e) {
            int idx = e * 256 + tid;
            int r = idx >> 4, c = idx & 15;
            As[c * 68 + r] = (k0 + c < K) ? A[(size_t)(m0 + r) * K + k0 + c] : 0.f;
            int rw = idx >> 6, cw = idx & 63;
            Ws[rw * 68 + cw] = (k0 + rw < K) ? W[(size_t)(k0 + rw) * N + n0 + cw] : 0.f;
        }
        __syncthreads();
        #pragma unroll
        for (int kk = 0; kk < 16; ++kk) {
            f32x4 a = *reinterpret_cast<const f32x4*>(&As[kk * 68 + tr * 4]);
            f32x4 b = *reinterpret_cast<const f32x4*>(&Ws[kk * 68 + tc * 4]);
            #pragma unroll
            for (int i = 0; i < 4; ++i)
                #pragma unroll
                for (int j = 0; j < 4; ++j)
                    acc[i][j] = fmaf(a[i], b[j], acc[i][j]);
        }
        __syncthreads();
    }
    f32x4 bo = *reinterpret_cast<const f32x4*>(&bias[n0 + tc * 4]);
    #pragma unroll
    for (int i = 0; i < 4; ++i) {
        int m = m0 + tr * 4 + i;
        if (OUT_BF16) {
            ushort4 u;
            u.x = f2bf(fmaxf(acc[i][0] + bo[0], 0.f));
            u.y = f2bf(fmaxf(acc[i][1] + bo[1], 0.f));
            u.z = f2bf(fmaxf(acc[i][2] + bo[2], 0.f));
            u.w = f2bf(fmaxf(acc[i][3] + bo[3], 0.f));
            *reinterpret_cast<ushort4*>(&((ushort*)Cout)[(size_t)m * N + n0 + tc * 4]) = u;
        } else {
            f32x4 v;
            #pragma unroll
            for (int j = 0; j < 4; ++j) v[j] = fmaxf(acc[i][j] + bo[j], 0.f);
            *reinterpret_cast<f32x4*>(&((float*)Cout)[(size_t)m * N + n0 + tc * 4]) = v;
        }
    }
}

// W_out (f32 [K][N]) -> Bp (bf16 [panel128][kb(128)][nl(128)][kj8]); smem >= 33792 B
__device__ __forceinline__ void convert_wout_body(
    int p, int kt, int tid, char* smem,
    const float* __restrict__ Wout, ushort* __restrict__ Bp)
{
    float* T = (float*)smem;                      // [64][132] (+4 pad)
    const int k0 = kt * 64;

    if (p < NPANEL - 1) {
        const int c4 = (tid & 31) * 4;
        const int r0 = tid >> 5;
        const float* src = Wout + (size_t)k0 * N_OUT + (size_t)p * 128 + c4;
        #pragma unroll
        for (int i = 0; i < 8; ++i) {
            const int r = r0 + i * 8;
            f32x4 v = *reinterpret_cast<const f32x4*>(src + (size_t)r * N_OUT);
            *reinterpret_cast<f32x4*>(&T[r * 132 + c4]) = v;
        }
    } else {
        const int c = tid & 31, r0 = tid >> 5;
        #pragma unroll
        for (int i = 0; i < 8; ++i) {
            const int r = r0 + i * 8;
            #pragma unroll
            for (int j = 0; j < 4; ++j) {
                int col = p * 128 + c * 4 + j;
                if (col > N_OUT - 1) col = N_OUT - 1;
                T[r * 132 + c * 4 + j] = Wout[(size_t)(k0 + r) * N_OUT + col];
            }
        }
    }
    __syncthreads();

    const size_t base = ((size_t)p * 128 + kt * 8) * 128 * 8;   // ushort index
    #pragma unroll
    for (int i = 0; i < 4; ++i) {
        const int v = tid + i * 256;
        const int kbl = v >> 7, nl = v & 127;
        s16x8 o;
        #pragma unroll
        for (int j = 0; j < 8; ++j) o[j] = (short)f2bf(T[(kbl * 8 + j) * 132 + nl]);
        *reinterpret_cast<s16x8*>(Bp + base + (size_t)v * 8) = o;
    }
}

// ---------------- fused stage: chain op (blocks [0,chainN)) ∥ convert band quarter ----------------
__global__ __launch_bounds__(256) void fused_stage(
    int stage, int chainN,
    const float* __restrict__ noise, const int* __restrict__ orders,
    const float* __restrict__ emb,
    const float* __restrict__ W1, const float* __restrict__ b1,
    const float* __restrict__ W2, const float* __restrict__ b2,
    const float* __restrict__ W3, const float* __restrict__ b3,
    float* __restrict__ x, float* __restrict__ h1, float* __restrict__ h2,
    ushort* __restrict__ h3,
    const float* __restrict__ Wout, ushort* __restrict__ Bp)
{
    __shared__ __align__(16) char smem[33792];
    const int bx = blockIdx.x;
    const int tid = threadIdx.x;
    if (bx < chainN) {
        if (stage == 0)      build_x_body(bx, tid, noise, orders, emb, x);
        else if (stage == 1) gemm_relu_body<false>(bx, tid, smem, x,  W1, b1, (void*)h1, 1024, 256,  116);
        else if (stage == 2) gemm_relu_body<false>(bx, tid, smem, h1, W2, b2, (void*)h2, 1024, 512,  256);
        else                 gemm_relu_body<true >(bx, tid, smem, h2, W3, b3, (void*)h3, 1024, 1024, 512);
    } else {
        const int c = bx - chainN;            // 0 .. CONV_BLOCKS_PER_STAGE-1
        const int p  = c % NPANEL;            // panel fast (row-band-major)
        const int kt = stage * 4 + c / NPANEL;
        convert_wout_body(p, kt, tid, smem, Wout, Bp);
    }
}

// ---------------- big GEMM: out = sigmoid(h3(bf16) @ Bp(bf16) + bout) ----------------
// m97 structure: 128x128 tile, BK=64, 4 waves (2x2), single-buffer LDS, 2 barriers/K-step.
// Epilogue: sigmoid -> LDS [64][132] stage -> 512 B-contiguous row-segment stores.
__global__ __launch_bounds__(256, 4) void gemm_out(
    const ushort* __restrict__ h3, const ushort* __restrict__ Bp,
    const float* __restrict__ bout, float* __restrict__ out)
{
    __shared__ __align__(16) char smem[33792];
    ushort* Alds = (ushort*)smem;             // [128 rows][8 units of 16B], XOR-swizzled source
    ushort* Blds = (ushort*)(smem + 16384);   // [kbl(8)][nl(128)][kj(8)]

    const int tid = threadIdx.x;
    const int lane = tid & 63;
    const int w = tid >> 6;
    const int wm = w >> 1, wn = w & 1;

    // XCD-grouped mapping: 8 m-blocks of a panel land on one XCD (B panel L2 reuse)
    const int raw = blockIdx.x;
    const int panel = (raw >> 6) * 8 + (raw & 7);
    const int mblk = (raw >> 3) & 7;
    if (panel >= NPANEL) return;
    const int m0 = mblk * 128;
    const int n0 = panel * 128;

    f32x4 acc[4][4] = {};

    const int arow = wm * 64 + (lane & 15);  // + fm*16
    const int ac0  = lane >> 4;
    const int bn   = wn * 64 + (lane & 15);  // + fn*16

    const ushort* BpPanel = Bp + (size_t)panel * (128 * 128 * 8);

    for (int kt = 0; kt < 16; ++kt) {
        const int k0 = kt * 64;
        // ---- stage A (16 KB) : 4 global_load_lds per thread, swizzled source ----
        #pragma unroll
        for (int i = 0; i < 4; ++i) {
            const int u = (w * 4 + i) * 64 + lane;       // linear 16B unit
            const int r = u >> 3, cc = u & 7;
            const ushort* src = h3 + (size_t)(m0 + r) * K_DIM + (k0 + ((cc ^ (r & 7)) << 3));
            lds_load16(src, (void*)&Alds[(w * 4 + i) * 512]);
        }
        // ---- stage B (16 KB) : contiguous chunk, linear copy ----
        const ushort* bsrc = BpPanel + (size_t)kt * 8192;
        #pragma unroll
        for (int i = 0; i < 4; ++i) {
            const int u = (w * 4 + i) * 64 + lane;
            lds_load16(bsrc + (size_t)u * 8, (void*)&Blds[(w * 4 + i) * 512]);
        }
        __syncthreads();   // compiler drains vmcnt(0) here

        // ---- compute: 16 ds_read_b128 + 32 MFMA per thread ----
        #pragma unroll
        for (int ks = 0; ks < 2; ++ks) {
            s16x8 af[4], bfr[4];
            #pragma unroll
            for (int fm = 0; fm < 4; ++fm) {
                const int r = arow + fm * 16;
                const int cc = (ks * 4 + ac0) ^ (r & 7);
                af[fm] = *reinterpret_cast<const s16x8*>(&Alds[r * 64 + cc * 8]);
            }
            const int kbl = ks * 4 + ac0;
            #pragma unroll
            for (int fn = 0; fn < 4; ++fn)
                bfr[fn] = *reinterpret_cast<const s16x8*>(&Blds[(kbl * 128 + bn + fn * 16) * 8]);
            #pragma unroll
            for (int fm = 0; fm < 4; ++fm)
                #pragma unroll
                for (int fn = 0; fn < 4; ++fn)
                    acc[fm][fn] = __builtin_amdgcn_mfma_f32_16x16x32_bf16(
                        af[fm], bfr[fn], acc[fm][fn], 0, 0, 0);
        }
        __syncthreads();
    }

    // ---- epilogue ----
    if (n0 + 128 <= N_OUT) {
        // full panel: sigmoid -> LDS [64][132] f32 -> 512 B row-segment stores (aligned-ish)
        float bo[4];
        #pragma unroll
        for (int fn = 0; fn < 4; ++fn) bo[fn] = bout[n0 + wn * 64 + fn * 16 + (lane & 15)];
        float* Elds = (float*)smem;
        #pragma unroll
        for (int p = 0; p < 2; ++p) {
            if (wm == p) {
                #pragma unroll
                for (int fm = 0; fm < 4; ++fm)
                    #pragma unroll
                    for (int fn = 0; fn < 4; ++fn)
                        #pragma unroll
                        for (int j = 0; j < 4; ++j) {
                            const int rl = fm * 16 + (lane >> 4) * 4 + j;      // 0..63
                            const int cl = wn * 64 + fn * 16 + (lane & 15);    // 0..127
                            const float z = acc[fm][fn][j] + bo[fn];
                            Elds[rl * 132 + cl] = 1.f / (1.f + __expf(-z));
                        }
            }
            __syncthreads();
            const size_t gb = (size_t)(m0 + p * 64) * N_OUT + n0;
            const int g = tid >> 5, c4 = (tid & 31) * 4;
            #pragma unroll
            for (int i = 0; i < 8; ++i) {
                const int rl = i * 8 + g;                                      // 0..63
                const f32x4 v = *reinterpret_cast<const f32x4*>(&Elds[rl * 132 + c4]);
                *reinterpret_cast<f32x4*>(&out[gb + (size_t)rl * N_OUT + c4]) = v;
            }
            __syncthreads();
        }
    } else {
        // last panel: scalar guarded stores
        const int rbase = m0 + wm * 64 + (lane >> 4) * 4;
        #pragma unroll
        for (int fn = 0; fn < 4; ++fn) {
            const int col = n0 + wn * 64 + fn * 16 + (lane & 15);
            const bool ok = col < N_OUT;
            const float bo = bout[ok ? col : (N_OUT - 1)];
            #pragma unroll
            for (int fm = 0; fm < 4; ++fm) {
                #pragma unroll
                for (int j = 0; j < 4; ++j) {
                    if (ok) {
                        const int row = rbase + fm * 16 + j;
                        const float z = acc[fm][fn][j] + bo;
                        out[(size_t)row * N_OUT + col] = 1.f / (1.f + __expf(-z));
                    }
                }
            }
        }
    }
}

// ---------------- fallback: fused f32->bf16 inside GEMM (round-1 kernel) ----------------
__global__ __launch_bounds__(256, 2) void gemm_out_fused(
    const ushort* __restrict__ h3, const float* __restrict__ Wout,
    const float* __restrict__ bout, float* __restrict__ out)
{
    __shared__ __align__(16) ushort Alds[2][128 * 64];
    __shared__ __align__(16) ushort Blds[2][64 * 128];

    const int tid = threadIdx.x;
    const int lane = tid & 63;
    const int w = tid >> 6;
    const int wm = w >> 1, wn = w & 1;

    const int raw = blockIdx.x;
    const int panel = (raw >> 6) * 8 + (raw & 7);
    const int mblk = (raw >> 3) & 7;
    if (panel >= NPANEL) return;
    const int m0 = mblk * 128;
    const int n0 = panel * 128;

    const int nl = tid & 127;
    const int kb0 = tid >> 7;
    int nc = n0 + nl; if (nc > N_OUT - 1) nc = N_OUT - 1;
    const float* Bsrc = Wout + nc;

    f32x4 acc[4][4] = {};
    float breg[32];

    const int arow = wm * 64 + (lane & 15);
    const int ac0  = lane >> 4;
    const int bn   = wn * 64 + (lane & 15);

    auto stageA = [&](int buf, int kt) {
        const int k0 = kt * 64;
        #pragma unroll
        for (int i = 0; i < 4; ++i) {
            const int u = (w * 4 + i) * 64 + lane;
            const int r = u >> 3, cc = u & 7;
            const ushort* src = h3 + (size_t)(m0 + r) * K_DIM + (k0 + ((cc ^ (r & 7)) << 3));
            lds_load16(src, (void*)&Alds[buf][(w * 4 + i) * 512]);
        }
    };
    auto loadB = [&](int kt) {
        const int k0 = kt * 64;
        #pragma unroll
        for (int g = 0; g < 4; ++g) {
            const int kb = kb0 + g * 2;
            #pragma unroll
            for (int i = 0; i < 8; ++i)
                breg[g * 8 + i] = Bsrc[(size_t)(k0 + kb * 8 + i) * N_OUT];
        }
    };
    auto writeB = [&](int buf) {
        #pragma unroll
        for (int g = 0; g < 4; ++g) {
            const int kb = kb0 + g * 2;
            s16x8 v;
            #pragma unroll
            for (int i = 0; i < 8; ++i) v[i] = (short)f2bf(breg[g * 8 + i]);
            *reinterpret_cast<s16x8*>(&Blds[buf][(kb * 128 + nl) * 8]) = v;
        }
    };
    auto compute = [&](int buf) {
        #pragma unroll
        for (int ks = 0; ks < 2; ++ks) {
            s16x8 af[4], bfr[4];
            #pragma unroll
            for (int fm = 0; fm < 4; ++fm) {
                const int r = arow + fm * 16;
                const int cc = (ks * 4 + ac0) ^ (r & 7);
                af[fm] = *reinterpret_cast<const s16x8*>(&Alds[buf][r * 64 + cc * 8]);
            }
            const int kb = ks * 4 + ac0;
            #pragma unroll
            for (int fn = 0; fn < 4; ++fn)
                bfr[fn] = *reinterpret_cast<const s16x8*>(&Blds[buf][(kb * 128 + bn + fn * 16) * 8]);
            #pragma unroll
            for (int fm = 0; fm < 4; ++fm)
                #pragma unroll
                for (int fn = 0; fn < 4; ++fn)
                    acc[fm][fn] = __builtin_amdgcn_mfma_f32_16x16x32_bf16(
                        af[fm], bfr[fn], acc[fm][fn], 0, 0, 0);
        }
    };

    stageA(0, 0);
    loadB(0);
    writeB(0);
    __syncthreads();

    for (int kt = 0; kt < 16; ++kt) {
        const int buf = kt & 1;
        if (kt + 1 < 16) {
            stageA(buf ^ 1, kt + 1);
            loadB(kt + 1);
        }
        compute(buf);
        if (kt + 1 < 16) writeB(buf ^ 1);
        __syncthreads();
    }

    const int rbase = m0 + wm * 64 + (lane >> 4) * 4;
    #pragma unroll
    for (int fn = 0; fn < 4; ++fn) {
        const int col = n0 + wn * 64 + fn * 16 + (lane & 15);
        const bool ok = col < N_OUT;
        const float bo = bout[ok ? col : (N_OUT - 1)];
        #pragma unroll
        for (int fm = 0; fm < 4; ++fm) {
            #pragma unroll
            for (int j = 0; j < 4; ++j) {
                if (ok) {
                    const int row = rbase + fm * 16 + j;
                    const float z = acc[fm][fn][j] + bo;
                    out[(size_t)row * N_OUT + col] = 1.f / (1.f + __expf(-z));
                }
            }
        }
    }
}

extern "C" void kernel_launch(void* const* d_in, const int* in_sizes, int n_in,
                              void* d_out, int out_size, void* d_ws, size_t ws_size,
                              hipStream_t stream)
{
    const float* noise = (const float*)d_in[0];
    const int*   orders = (const int*)d_in[1];
    const float* emb   = (const float*)d_in[2];
    const float* W1 = (const float*)d_in[3];
    const float* b1 = (const float*)d_in[4];
    const float* W2 = (const float*)d_in[5];
    const float* b2 = (const float*)d_in[6];
    const float* W3 = (const float*)d_in[7];
    const float* b3 = (const float*)d_in[8];
    const float* Wout = (const float*)d_in[9];
    const float* bout = (const float*)d_in[10];

    char* ws = (char*)d_ws;
    float*  x  = (float*)(ws);               // 475 KB
    float*  h1 = (float*)(ws + 0x80000);     // 1 MB
    float*  h2 = (float*)(ws + 0x180000);    // 2 MB
    ushort* h3 = (ushort*)(ws + 0x380000);   // 2 MB (bf16)
    ushort* Bp = (ushort*)(ws + 0x580000);   // 517*128*128*8*2 = 135.5 MB
    const size_t need = 0x580000 + (size_t)NPANEL * 128 * 128 * 8 * 2;

    const bool pre = (ws_size >= need);
    const int convN = pre ? CONV_BLOCKS_PER_STAGE : 0;
    const int chainN[4] = {464, 64, 128, 256};

    for (int s = 0; s < 4; ++s)
        fused_stage<<<chainN[s] + convN, 256, 0, stream>>>(
            s, chainN[s], noise, orders, emb, W1, b1, W2, b2, W3, b3,
            x, h1, h2, h3, Wout, Bp);

    if (pre)
        gemm_out<<<4160, 256, 0, stream>>>(h3, Bp, bout, (float*)d_out);
    else
        gemm_out_fused<<<4160, 256, 0, stream>>>(h3, Wout, bout, (float*)d_out);
}